// Round 4
// baseline (358.213 us; speedup 1.0000x reference)
//
#include <hip/hip_runtime.h>
#include <hip/hip_bf16.h>

typedef __bf16 bf16x8 __attribute__((ext_vector_type(8)));
typedef short short8 __attribute__((ext_vector_type(8)));
typedef float f32x4 __attribute__((ext_vector_type(4)));

union BF8 { short8 s; bf16x8 b; };

#define N_NODES 4096
#define F_IN 512
#define F_OUT 64
#define NHEAD 8
#define HID 512
#define NCLS 10
#define GAT_ALPHA 0.2f
#define NEGINF -9e15f
#define MSPLIT 4
#define WST 4128          // WhbT row stride in elements (8256 B, breaks 2^13 alias)
#define ABST 66           // adjbits row stride in 8B words (528 B)

__device__ inline unsigned short f2bf(float f) {
  unsigned u = __builtin_bit_cast(unsigned, f);
  unsigned r = (u + 0x7FFFu + ((u >> 16) & 1u)) >> 16;
  return (unsigned short)r;
}
__device__ inline float bf2f(unsigned short h) {
  unsigned u = ((unsigned)h) << 16;
  return __builtin_bit_cast(float, u);
}

// ---------------- pack adjacency to bits: adjbits[n][m/64] (padded) --------
__global__ __launch_bounds__(256) void pack_adj_kernel(
    const int* __restrict__ adj, unsigned long long* __restrict__ bits) {
  int wid = blockIdx.x * 4 + (threadIdx.x >> 6);   // word index [0, 4096*64)
  int l = threadIdx.x & 63;
  unsigned long long m = __ballot(adj[(size_t)wid * 64 + l] != 0);
  if (l == 0) {
    int row = wid >> 6, w = wid & 63;
    bits[(size_t)row * ABST + w] = m;
  }
}

// ---------------- GEMM1: Whcat[n][h*64+o] = x @ W, also WhbT bf16 ----------
__global__ __launch_bounds__(256) void gemm1_kernel(
    const float* __restrict__ x, const float* __restrict__ W,
    float* __restrict__ Whcat, unsigned short* __restrict__ WhbT) {
  __shared__ short As[64 * 40];   // [row][k] bf16, stride 40 (pad)
  __shared__ short Bs[64 * 40];   // [o][k]   bf16, stride 40 (pad)
  const int bx = blockIdx.x;      // 64-row tile
  const int h  = blockIdx.y;      // head
  const int t  = threadIdx.x;
  const int w  = t >> 6, l = t & 63;
  const int lr = l & 15, ls = l >> 4;
  f32x4 acc[4] = {};
  for (int k0 = 0; k0 < F_IN; k0 += 32) {
    {   // stage A: 64 rows x 32 k
      int r = t >> 2, c0 = (t & 3) * 8;
      const float* src = x + (bx * 64 + r) * F_IN + k0 + c0;
      float4 v0 = *(const float4*)src;
      float4 v1 = *(const float4*)(src + 4);
      short8 sv;
      sv[0]=f2bf(v0.x); sv[1]=f2bf(v0.y); sv[2]=f2bf(v0.z); sv[3]=f2bf(v0.w);
      sv[4]=f2bf(v1.x); sv[5]=f2bf(v1.y); sv[6]=f2bf(v1.z); sv[7]=f2bf(v1.w);
      *(short8*)&As[r * 40 + c0] = sv;
    }
    {   // stage B: W[h][k0+kk][o] -> Bs[o][kk] (transposed)
      int kk = t >> 3, o0 = (t & 7) * 8;
      const float* src = W + ((h * F_IN) + k0 + kk) * F_OUT + o0;
      float4 v0 = *(const float4*)src;
      float4 v1 = *(const float4*)(src + 4);
      float vv[8] = {v0.x, v0.y, v0.z, v0.w, v1.x, v1.y, v1.z, v1.w};
      #pragma unroll
      for (int i = 0; i < 8; ++i) Bs[(o0 + i) * 40 + kk] = f2bf(vv[i]);
    }
    __syncthreads();
    BF8 a; a.s = *(short8*)&As[(w * 16 + lr) * 40 + ls * 8];
    #pragma unroll
    for (int fc = 0; fc < 4; ++fc) {
      BF8 b; b.s = *(short8*)&Bs[(fc * 16 + lr) * 40 + ls * 8];
      acc[fc] = __builtin_amdgcn_mfma_f32_16x16x32_bf16(a.b, b.b, acc[fc], 0, 0, 0);
    }
    __syncthreads();
  }
  #pragma unroll
  for (int fc = 0; fc < 4; ++fc)
    #pragma unroll
    for (int j = 0; j < 4; ++j) {
      int row = bx * 64 + w * 16 + ls * 4 + j;   // C/D: row=(l>>4)*4+j
      int col = fc * 16 + lr;                    // C/D: col=l&15
      float v = acc[fc][j];
      Whcat[row * HID + h * F_OUT + col] = v;
      WhbT[(size_t)(h * F_OUT + col) * WST + row] = f2bf(v);
    }
}

// ---------------- f1/f2 + separable-exp tables -----------------------------
__global__ __launch_bounds__(512) void f12_kernel(
    const float* __restrict__ Whcat, const float* __restrict__ a1,
    const float* __restrict__ a2, float* __restrict__ f1, float* __restrict__ f2,
    float* __restrict__ E1, float* __restrict__ E1s,
    float* __restrict__ E2, float* __restrict__ E2s) {
  int n = blockIdx.x;
  int w = threadIdx.x >> 6, l = threadIdx.x & 63;
  float v = Whcat[n * HID + w * F_OUT + l];
  float s1 = v * a1[w * F_OUT + l];
  float s2 = v * a2[w * F_OUT + l];
  #pragma unroll
  for (int off = 32; off > 0; off >>= 1) {
    s1 += __shfl_xor(s1, off, 64);
    s2 += __shfl_xor(s2, off, 64);
  }
  if (l == 0) {
    f1[w * N_NODES + n] = s1; f2[w * N_NODES + n] = s2;
    E1[w * N_NODES + n]  = __expf(s1);
    E1s[w * N_NODES + n] = __expf(GAT_ALPHA * s1);
    E2[w * N_NODES + n]  = __expf(s2);
    E2s[w * N_NODES + n] = __expf(GAT_ALPHA * s2);
  }
}

// ---------------- ATT1: m-split flash GAT, partials to ws ------------------
__global__ __launch_bounds__(512, 4) void att1_kernel(
    const unsigned long long* __restrict__ adjbits,
    const float* __restrict__ f1, const float* __restrict__ f2,
    const float* __restrict__ E1, const float* __restrict__ E1s,
    const float* __restrict__ E2, const float* __restrict__ E2s,
    const unsigned short* __restrict__ WhbT,
    float* __restrict__ accP, float* __restrict__ SP) {
  const int nb = blockIdx.x * 16;
  const int q  = blockIdx.y;               // m-quarter
  const int t = threadIdx.x;
  const int h = t >> 6;                // wave = head
  const int l = t & 63;
  const int r = l & 15, s = l >> 4;
  const int row = nb + r;
  const float t1  = -f1[h * N_NODES + row];
  const float e1  = E1[h * N_NODES + row];
  const float e1s = E1s[h * N_NODES + row];
  const float* __restrict__ f2h  = f2  + h * N_NODES;
  const float* __restrict__ E2h  = E2  + h * N_NODES;
  const float* __restrict__ E2sh = E2s + h * N_NODES;
  const unsigned long long* __restrict__ abrow = adjbits + (size_t)row * ABST;
  const unsigned short* __restrict__ bbase = WhbT + (size_t)(h * F_OUT + r) * WST;
  float S = 0.f;
  f32x4 acc[4] = {};
  const int tb0 = q * (N_NODES / MSPLIT);
  const int tb1 = tb0 + (N_NODES / MSPLIT);
  #pragma unroll 2
  for (int tb = tb0; tb < tb1; tb += 64) {
    const unsigned long long mask = abrow[tb >> 6];
    // stage all 8 B-fragments first (independent 16B L2 loads, overlap)
    BF8 b[8];
    #pragma unroll
    for (int fc = 0; fc < 4; ++fc)
      #pragma unroll
      for (int kf = 0; kf < 2; ++kf)
        b[fc * 2 + kf].s = *(const short8*)(bbase + (size_t)fc * 16 * WST + tb + kf * 32 + s * 8);
    BF8 afr[2];
    #pragma unroll
    for (int kf = 0; kf < 2; ++kf) {
      const int base = tb + kf * 32 + s * 8;
      const unsigned byte = (unsigned)(mask >> (kf * 32 + s * 8)) & 0xffu;
      float4 fa = *(const float4*)(f2h + base);
      float4 fb = *(const float4*)(f2h + base + 4);
      float4 ea = *(const float4*)(E2h + base);
      float4 eb = *(const float4*)(E2h + base + 4);
      float4 sa = *(const float4*)(E2sh + base);
      float4 sb = *(const float4*)(E2sh + base + 4);
      float fv[8] = {fa.x, fa.y, fa.z, fa.w, fb.x, fb.y, fb.z, fb.w};
      float ev[8] = {ea.x, ea.y, ea.z, ea.w, eb.x, eb.y, eb.z, eb.w};
      float sv[8] = {sa.x, sa.y, sa.z, sa.w, sb.x, sb.y, sb.z, sb.w};
      #pragma unroll
      for (int j = 0; j < 8; ++j) {
        float pe = (fv[j] > t1) ? (e1 * ev[j]) : (e1s * sv[j]);
        pe = ((byte >> j) & 1u) ? pe : 0.f;
        S += pe;
        afr[kf].b[j] = (__bf16)pe;
      }
    }
    #pragma unroll
    for (int fc = 0; fc < 4; ++fc)
      #pragma unroll
      for (int kf = 0; kf < 2; ++kf)
        acc[fc] = __builtin_amdgcn_mfma_f32_16x16x32_bf16(afr[kf].b, b[fc * 2 + kf].b, acc[fc], 0, 0, 0);
  }
  // partial row sums: reduce over the 4 s-lanes of each row
  S += __shfl_xor(S, 16, 64);
  S += __shfl_xor(S, 32, 64);
  if (s == 0) SP[((size_t)q * NHEAD + h) * N_NODES + row] = S;
  #pragma unroll
  for (int fc = 0; fc < 4; ++fc)
    #pragma unroll
    for (int j = 0; j < 4; ++j) {
      int n = nb + s * 4 + j;
      int col = h * F_OUT + fc * 16 + r;
      accP[((size_t)q * N_NODES + n) * HID + col] = acc[fc][j];
    }
}

// ---------------- ATT1 reduce: combine partials, ELU, write hcat -----------
__global__ __launch_bounds__(512) void att1_reduce_kernel(
    const float* __restrict__ accP, const float* __restrict__ SP,
    unsigned short* __restrict__ hcat) {
  const int n = blockIdx.x;
  const int c = threadIdx.x;           // hid col
  const int h = c >> 6;
  float Ssum = 0.f;
  #pragma unroll
  for (int q = 0; q < MSPLIT; ++q) Ssum += SP[((size_t)q * NHEAD + h) * N_NODES + n];
  float v = 0.f;
  #pragma unroll
  for (int q = 0; q < MSPLIT; ++q) v += accP[((size_t)q * N_NODES + n) * HID + c];
  v /= Ssum;
  float e = v > 0.f ? v : (__expf(v) - 1.0f);
  hcat[(size_t)n * HID + c] = f2bf(e);
}

// ---------------- GEMM2: Wh2 = hcat @ Wo, g tables -------------------------
__global__ __launch_bounds__(256) void gemm2_kernel(
    const unsigned short* __restrict__ hcat, const float* __restrict__ Wo,
    const float* __restrict__ ao1, const float* __restrict__ ao2,
    float* __restrict__ Wh2, float* __restrict__ g1, float* __restrict__ g2,
    float* __restrict__ Eg1, float* __restrict__ Eg1s,
    float* __restrict__ Eg2, float* __restrict__ Eg2s) {
  int n = blockIdx.x * 4 + (threadIdx.x >> 6);
  int l = threadIdx.x & 63;
  float acc[NCLS] = {};
  for (int k = l; k < HID; k += 64) {
    float hv = bf2f(hcat[n * HID + k]);
    const float* wrow = Wo + k * NCLS;
    #pragma unroll
    for (int c = 0; c < NCLS; ++c) acc[c] += hv * wrow[c];
  }
  #pragma unroll
  for (int c = 0; c < NCLS; ++c)
    #pragma unroll
    for (int off = 32; off > 0; off >>= 1) acc[c] += __shfl_xor(acc[c], off, 64);
  if (l == 0) {
    float s1 = 0.f, s2 = 0.f;
    #pragma unroll
    for (int c = 0; c < NCLS; ++c) {
      Wh2[n * NCLS + c] = acc[c];
      s1 += acc[c] * ao1[c];
      s2 += acc[c] * ao2[c];
    }
    g1[n] = s1; g2[n] = s2;
    Eg1[n]  = __expf(s1); Eg1s[n] = __expf(GAT_ALPHA * s1);
    Eg2[n]  = __expf(s2); Eg2s[n] = __expf(GAT_ALPHA * s2);
  }
}

// ---------------- ATT2 + log_softmax (no-max, separable exp) ---------------
__global__ __launch_bounds__(256) void att2_kernel(
    const unsigned long long* __restrict__ adjbits,
    const float* __restrict__ g1, const float* __restrict__ g2,
    const float* __restrict__ Eg1, const float* __restrict__ Eg1s,
    const float* __restrict__ Eg2, const float* __restrict__ Eg2s,
    const float* __restrict__ Wh2, float* __restrict__ out) {
  int n = blockIdx.x * 4 + (threadIdx.x >> 6);
  int l = threadIdx.x & 63;
  const float t1  = -g1[n];
  const float e1  = Eg1[n];
  const float e1s = Eg1s[n];
  const unsigned long long* __restrict__ abrow = adjbits + (size_t)n * ABST;
  float S = 0.f;
  float acc[NCLS] = {};
  for (int tb = 0; tb < N_NODES; tb += 64) {
    int m = tb + l;
    unsigned long long bits = abrow[tb >> 6];
    float f2v = g2[m];
    float p = (f2v > t1) ? (e1 * Eg2[m]) : (e1s * Eg2s[m]);
    p = ((bits >> l) & 1ull) ? p : 0.f;
    S += p;
    const float* wrow = Wh2 + m * NCLS;
    #pragma unroll
    for (int c = 0; c < NCLS; ++c) acc[c] += p * wrow[c];
  }
  #pragma unroll
  for (int off = 32; off > 0; off >>= 1) S += __shfl_xor(S, off, 64);
  #pragma unroll
  for (int c = 0; c < NCLS; ++c)
    #pragma unroll
    for (int off = 32; off > 0; off >>= 1) acc[c] += __shfl_xor(acc[c], off, 64);
  float rS = 1.0f / S;
  float lo[NCLS]; float mx = -1e30f;
  #pragma unroll
  for (int c = 0; c < NCLS; ++c) { lo[c] = acc[c] * rS; mx = fmaxf(mx, lo[c]); }
  float se = 0.f;
  #pragma unroll
  for (int c = 0; c < NCLS; ++c) se += __expf(lo[c] - mx);
  float lse = mx + __logf(se);
  if (l == 0) {
    #pragma unroll
    for (int c = 0; c < NCLS; ++c) out[n * NCLS + c] = lo[c] - lse;
  }
}

extern "C" void kernel_launch(void* const* d_in, const int* in_sizes, int n_in,
                              void* d_out, int out_size, void* d_ws, size_t ws_size,
                              hipStream_t stream) {
  (void)in_sizes; (void)n_in; (void)out_size; (void)ws_size;
  const float* x   = (const float*)d_in[0];
  const int*   adj = (const int*)d_in[1];
  const float* W   = (const float*)d_in[2];
  const float* a1  = (const float*)d_in[3];
  const float* a2  = (const float*)d_in[4];
  const float* Wo  = (const float*)d_in[5];
  const float* ao1 = (const float*)d_in[6];
  const float* ao2 = (const float*)d_in[7];
  float* out = (float*)d_out;

  char* ws = (char*)d_ws;
  unsigned long long* adjbits = (unsigned long long*)ws; ws += (size_t)N_NODES * ABST * 8;
  float* Whcat        = (float*)ws;          ws += (size_t)N_NODES * HID * 4;
  unsigned short* WhbT= (unsigned short*)ws; ws += (size_t)HID * WST * 2;
  unsigned short* hcat= (unsigned short*)ws; ws += (size_t)N_NODES * HID * 2;
  float* accP         = (float*)ws;          ws += (size_t)MSPLIT * N_NODES * HID * 4;
  float* SP           = (float*)ws;          ws += (size_t)MSPLIT * NHEAD * N_NODES * 4;
  float* f1           = (float*)ws;          ws += (size_t)NHEAD * N_NODES * 4;
  float* f2           = (float*)ws;          ws += (size_t)NHEAD * N_NODES * 4;
  float* E1           = (float*)ws;          ws += (size_t)NHEAD * N_NODES * 4;
  float* E1s          = (float*)ws;          ws += (size_t)NHEAD * N_NODES * 4;
  float* E2           = (float*)ws;          ws += (size_t)NHEAD * N_NODES * 4;
  float* E2s          = (float*)ws;          ws += (size_t)NHEAD * N_NODES * 4;
  float* Wh2          = (float*)ws;          ws += (size_t)N_NODES * NCLS * 4;
  float* g1           = (float*)ws;          ws += (size_t)N_NODES * 4;
  float* g2           = (float*)ws;          ws += (size_t)N_NODES * 4;
  float* Eg1          = (float*)ws;          ws += (size_t)N_NODES * 4;
  float* Eg1s         = (float*)ws;          ws += (size_t)N_NODES * 4;
  float* Eg2          = (float*)ws;          ws += (size_t)N_NODES * 4;
  float* Eg2s         = (float*)ws;          ws += (size_t)N_NODES * 4;

  pack_adj_kernel<<<N_NODES * (N_NODES / 64) / 4, 256, 0, stream>>>(adj, adjbits);
  gemm1_kernel<<<dim3(64, 8), 256, 0, stream>>>(x, W, Whcat, WhbT);
  f12_kernel<<<N_NODES, 512, 0, stream>>>(Whcat, a1, a2, f1, f2, E1, E1s, E2, E2s);
  att1_kernel<<<dim3(N_NODES / 16, MSPLIT), 512, 0, stream>>>(adjbits, f1, f2, E1, E1s, E2, E2s, WhbT, accP, SP);
  att1_reduce_kernel<<<N_NODES, 512, 0, stream>>>(accP, SP, hcat);
  gemm2_kernel<<<N_NODES / 4, 256, 0, stream>>>(hcat, Wo, ao1, ao2, Wh2, g1, g2, Eg1, Eg1s, Eg2, Eg2s);
  att2_kernel<<<N_NODES / 4, 256, 0, stream>>>(adjbits, g1, g2, Eg1, Eg1s, Eg2, Eg2s, Wh2, out);
}

// Round 5
// 182.989 us; speedup vs baseline: 1.9576x; 1.9576x over previous
//
#include <hip/hip_runtime.h>
#include <hip/hip_bf16.h>

typedef __bf16 bf16x8 __attribute__((ext_vector_type(8)));
typedef short short8 __attribute__((ext_vector_type(8)));
typedef float f32x4 __attribute__((ext_vector_type(4)));

union BF8 { short8 s; bf16x8 b; };

#define N_NODES 4096
#define F_IN 512
#define F_OUT 64
#define NHEAD 8
#define HID 512
#define NCLS 10
#define GAT_ALPHA 0.2f
#define NEGINF -9e15f
#define MSPLIT 4
#define WST 4096          // WhbT row stride (padding reverted: it hurt, r4)
#define NWORD (N_NODES / 64)

__device__ inline unsigned short f2bf(float f) {
  unsigned u = __builtin_bit_cast(unsigned, f);
  unsigned r = (u + 0x7FFFu + ((u >> 16) & 1u)) >> 16;
  return (unsigned short)r;
}
__device__ inline float bf2f(unsigned short h) {
  unsigned u = ((unsigned)h) << 16;
  return __builtin_bit_cast(float, u);
}

// ---------------- pack adjacency to bits: adjbits[n][m/64] -----------------
__global__ __launch_bounds__(256) void pack_adj_kernel(
    const int* __restrict__ adj, unsigned long long* __restrict__ bits) {
  int wid = blockIdx.x * 4 + (threadIdx.x >> 6);   // word index [0, 4096*64)
  int l = threadIdx.x & 63;
  unsigned long long m = __ballot(adj[(size_t)wid * 64 + l] != 0);
  if (l == 0) bits[wid] = m;
}

// ---------------- GEMM1: Whcat[n][h*64+o] = x @ W, also WhbT bf16 ----------
__global__ __launch_bounds__(256) void gemm1_kernel(
    const float* __restrict__ x, const float* __restrict__ W,
    float* __restrict__ Whcat, unsigned short* __restrict__ WhbT) {
  __shared__ short As[64 * 40];   // [row][k] bf16, stride 40 (pad)
  __shared__ short Bs[64 * 40];   // [o][k]   bf16, stride 40 (pad)
  const int bx = blockIdx.x;      // 64-row tile
  const int h  = blockIdx.y;      // head
  const int t  = threadIdx.x;
  const int w  = t >> 6, l = t & 63;
  const int lr = l & 15, ls = l >> 4;
  f32x4 acc[4] = {};
  for (int k0 = 0; k0 < F_IN; k0 += 32) {
    {   // stage A: 64 rows x 32 k
      int r = t >> 2, c0 = (t & 3) * 8;
      const float* src = x + (bx * 64 + r) * F_IN + k0 + c0;
      float4 v0 = *(const float4*)src;
      float4 v1 = *(const float4*)(src + 4);
      short8 sv;
      sv[0]=f2bf(v0.x); sv[1]=f2bf(v0.y); sv[2]=f2bf(v0.z); sv[3]=f2bf(v0.w);
      sv[4]=f2bf(v1.x); sv[5]=f2bf(v1.y); sv[6]=f2bf(v1.z); sv[7]=f2bf(v1.w);
      *(short8*)&As[r * 40 + c0] = sv;
    }
    {   // stage B: W[h][k0+kk][o] -> Bs[o][kk] (transposed)
      int kk = t >> 3, o0 = (t & 7) * 8;
      const float* src = W + ((h * F_IN) + k0 + kk) * F_OUT + o0;
      float4 v0 = *(const float4*)src;
      float4 v1 = *(const float4*)(src + 4);
      float vv[8] = {v0.x, v0.y, v0.z, v0.w, v1.x, v1.y, v1.z, v1.w};
      #pragma unroll
      for (int i = 0; i < 8; ++i) Bs[(o0 + i) * 40 + kk] = f2bf(vv[i]);
    }
    __syncthreads();
    BF8 a; a.s = *(short8*)&As[(w * 16 + lr) * 40 + ls * 8];
    #pragma unroll
    for (int fc = 0; fc < 4; ++fc) {
      BF8 b; b.s = *(short8*)&Bs[(fc * 16 + lr) * 40 + ls * 8];
      acc[fc] = __builtin_amdgcn_mfma_f32_16x16x32_bf16(a.b, b.b, acc[fc], 0, 0, 0);
    }
    __syncthreads();
  }
  #pragma unroll
  for (int fc = 0; fc < 4; ++fc)
    #pragma unroll
    for (int j = 0; j < 4; ++j) {
      int row = bx * 64 + w * 16 + ls * 4 + j;   // C/D: row=(l>>4)*4+j
      int col = fc * 16 + lr;                    // C/D: col=l&15
      float v = acc[fc][j];
      Whcat[row * HID + h * F_OUT + col] = v;
      WhbT[(size_t)(h * F_OUT + col) * WST + row] = f2bf(v);
    }
}

// ---------------- f1/f2 + separable-exp tables -----------------------------
__global__ __launch_bounds__(512) void f12_kernel(
    const float* __restrict__ Whcat, const float* __restrict__ a1,
    const float* __restrict__ a2, float* __restrict__ f1, float* __restrict__ f2,
    float* __restrict__ E1, float* __restrict__ E1s,
    float* __restrict__ E2, float* __restrict__ E2s) {
  int n = blockIdx.x;
  int w = threadIdx.x >> 6, l = threadIdx.x & 63;
  float v = Whcat[n * HID + w * F_OUT + l];
  float s1 = v * a1[w * F_OUT + l];
  float s2 = v * a2[w * F_OUT + l];
  #pragma unroll
  for (int off = 32; off > 0; off >>= 1) {
    s1 += __shfl_xor(s1, off, 64);
    s2 += __shfl_xor(s2, off, 64);
  }
  if (l == 0) {
    f1[w * N_NODES + n] = s1; f2[w * N_NODES + n] = s2;
    E1[w * N_NODES + n]  = __expf(s1);
    E1s[w * N_NODES + n] = __expf(GAT_ALPHA * s1);
    E2[w * N_NODES + n]  = __expf(s2);
    E2s[w * N_NODES + n] = __expf(GAT_ALPHA * s2);
  }
}

// ---------------- ATT1: 64-row tiles, DMA-staged B, per-wave dbuf ----------
// wave = head; block = 64 rows; grid.y = column quarter (MSPLIT).
// LDS: Bt[buf][head][64 out][64 col] bf16, XOR-swizzled within rows (both
// sides: pre-swizzled DMA source + swizzled ds_read). No __syncthreads —
// each wave owns its LDS region; staging ordered by counted vmcnt.
__global__ __launch_bounds__(512, 2) void att1_kernel(
    const unsigned long long* __restrict__ adjbits,
    const float* __restrict__ f1, const float* __restrict__ f2,
    const float* __restrict__ E1, const float* __restrict__ E1s,
    const float* __restrict__ E2, const float* __restrict__ E2s,
    const unsigned short* __restrict__ WhbT,
    float* __restrict__ accP, float* __restrict__ SP) {
  __shared__ __align__(16) short Bt[2][NHEAD][64 * 64];
  const int nb = blockIdx.x * 64;
  const int q  = blockIdx.y;
  const int t  = threadIdx.x;
  const int h  = t >> 6;               // wave = head
  const int l  = t & 63;
  const int r  = l & 15, s = l >> 4;

  // per-row-group scalars (rows nb + rg*16 + r)
  float t1[4], e1[4], e1s[4];
  #pragma unroll
  for (int rg = 0; rg < 4; ++rg) {
    int idx = h * N_NODES + nb + rg * 16 + r;
    t1[rg]  = -f1[idx];
    e1[rg]  = E1[idx];
    e1s[rg] = E1s[idx];
  }
  const float* __restrict__ f2h  = f2  + h * N_NODES;
  const float* __restrict__ E2h  = E2  + h * N_NODES;
  const float* __restrict__ E2sh = E2s + h * N_NODES;

  // DMA source base: lane covers row (l>>3) of each 8-row octet, swizzled col
  const int swzcol = ((l & 7) ^ (l >> 3)) * 8;       // element index, involution
  const unsigned short* gsrc0 =
      WhbT + (size_t)(h * F_OUT + (l >> 3)) * WST + swzcol;

  const int tb0 = q * (N_NODES / MSPLIT);
  const int NIT = (N_NODES / MSPLIT) / 64;           // 16

  // prologue: stage buffer 0
  #pragma unroll
  for (int i = 0; i < 8; ++i)
    __builtin_amdgcn_global_load_lds(
        (const __attribute__((address_space(1))) void*)(gsrc0 + tb0 + (size_t)i * 8 * WST),
        (__attribute__((address_space(3))) void*)&Bt[0][h][i * 512], 16, 0, 0);

  float S[4] = {};
  f32x4 acc[4][4] = {};
  for (int it = 0; it < NIT; ++it) {
    const int tb  = tb0 + it * 64;
    const int cur = it & 1;
    // issue next tile's DMA first (T14 issue-early)
    if (it + 1 < NIT) {
      #pragma unroll
      for (int i = 0; i < 8; ++i)
        __builtin_amdgcn_global_load_lds(
            (const __attribute__((address_space(1))) void*)(gsrc0 + tb + 64 + (size_t)i * 8 * WST),
            (__attribute__((address_space(3))) void*)&Bt[cur ^ 1][h][i * 512], 16, 0, 0);
    }
    // masks for the 4 row-groups
    unsigned long long mk[4];
    #pragma unroll
    for (int rg = 0; rg < 4; ++rg)
      mk[rg] = adjbits[(size_t)(nb + rg * 16 + r) * NWORD + (tb >> 6)] >> (s * 8);
    // logits -> p (bf16 A-fragments), per-row partial sums
    BF8 afr[4][2];
    #pragma unroll
    for (int kf = 0; kf < 2; ++kf) {
      const int cb = tb + kf * 32 + s * 8;
      float4 fa = *(const float4*)(f2h + cb);
      float4 fb = *(const float4*)(f2h + cb + 4);
      float4 ea = *(const float4*)(E2h + cb);
      float4 eb = *(const float4*)(E2h + cb + 4);
      float4 sa = *(const float4*)(E2sh + cb);
      float4 sb = *(const float4*)(E2sh + cb + 4);
      float fv[8] = {fa.x, fa.y, fa.z, fa.w, fb.x, fb.y, fb.z, fb.w};
      float ev[8] = {ea.x, ea.y, ea.z, ea.w, eb.x, eb.y, eb.z, eb.w};
      float sv[8] = {sa.x, sa.y, sa.z, sa.w, sb.x, sb.y, sb.z, sb.w};
      #pragma unroll
      for (int rg = 0; rg < 4; ++rg) {
        const unsigned byte = (unsigned)(mk[rg] >> (kf * 32)) & 0xffu;
        #pragma unroll
        for (int j = 0; j < 8; ++j) {
          float pe = (fv[j] > t1[rg]) ? (e1[rg] * ev[j]) : (e1s[rg] * sv[j]);
          pe = ((byte >> j) & 1u) ? pe : 0.f;
          S[rg] += pe;
          afr[rg][kf].b[j] = (__bf16)pe;
        }
      }
    }
    // current buffer's 8 DMA ops are the oldest outstanding; leave the 8
    // just-issued next-tile ops in flight.
    if (it + 1 < NIT) asm volatile("s_waitcnt vmcnt(8)" ::: "memory");
    else              asm volatile("s_waitcnt vmcnt(0)" ::: "memory");
    // B fragments from LDS (swizzled read) + MFMA
    #pragma unroll
    for (int kf = 0; kf < 2; ++kf)
      #pragma unroll
      for (int fc = 0; fc < 4; ++fc) {
        BF8 b;
        b.s = *(short8*)&Bt[cur][h][(fc * 16 + r) * 64 + ((kf * 32 + s * 8) ^ ((r & 7) * 8))];
        #pragma unroll
        for (int rg = 0; rg < 4; ++rg)
          acc[rg][fc] = __builtin_amdgcn_mfma_f32_16x16x32_bf16(afr[rg][kf].b, b.b, acc[rg][fc], 0, 0, 0);
      }
  }
  // partial row sums: reduce over the 4 s-lanes of each row
  #pragma unroll
  for (int rg = 0; rg < 4; ++rg) {
    S[rg] += __shfl_xor(S[rg], 16, 64);
    S[rg] += __shfl_xor(S[rg], 32, 64);
    if (s == 0) SP[((size_t)q * NHEAD + h) * N_NODES + nb + rg * 16 + r] = S[rg];
  }
  #pragma unroll
  for (int rg = 0; rg < 4; ++rg)
    #pragma unroll
    for (int fc = 0; fc < 4; ++fc)
      #pragma unroll
      for (int j = 0; j < 4; ++j) {
        int n = nb + rg * 16 + s * 4 + j;          // C/D: row=(l>>4)*4+j
        int col = h * F_OUT + fc * 16 + r;         // C/D: col=l&15
        accP[((size_t)q * N_NODES + n) * HID + col] = acc[rg][fc][j];
      }
}

// ---------------- ATT1 reduce: combine partials, ELU, write hcat -----------
__global__ __launch_bounds__(512) void att1_reduce_kernel(
    const float* __restrict__ accP, const float* __restrict__ SP,
    unsigned short* __restrict__ hcat) {
  const int n = blockIdx.x;
  const int c = threadIdx.x;           // hid col
  const int h = c >> 6;
  float Ssum = 0.f;
  #pragma unroll
  for (int q = 0; q < MSPLIT; ++q) Ssum += SP[((size_t)q * NHEAD + h) * N_NODES + n];
  float v = 0.f;
  #pragma unroll
  for (int q = 0; q < MSPLIT; ++q) v += accP[((size_t)q * N_NODES + n) * HID + c];
  v /= Ssum;
  float e = v > 0.f ? v : (__expf(v) - 1.0f);
  hcat[(size_t)n * HID + c] = f2bf(e);
}

// ---------------- GEMM2: Wh2 = hcat @ Wo, g tables -------------------------
__global__ __launch_bounds__(256) void gemm2_kernel(
    const unsigned short* __restrict__ hcat, const float* __restrict__ Wo,
    const float* __restrict__ ao1, const float* __restrict__ ao2,
    float* __restrict__ Wh2, float* __restrict__ g1, float* __restrict__ g2,
    float* __restrict__ Eg1, float* __restrict__ Eg1s,
    float* __restrict__ Eg2, float* __restrict__ Eg2s) {
  int n = blockIdx.x * 4 + (threadIdx.x >> 6);
  int l = threadIdx.x & 63;
  float acc[NCLS] = {};
  for (int k = l; k < HID; k += 64) {
    float hv = bf2f(hcat[n * HID + k]);
    const float* wrow = Wo + k * NCLS;
    #pragma unroll
    for (int c = 0; c < NCLS; ++c) acc[c] += hv * wrow[c];
  }
  #pragma unroll
  for (int c = 0; c < NCLS; ++c)
    #pragma unroll
    for (int off = 32; off > 0; off >>= 1) acc[c] += __shfl_xor(acc[c], off, 64);
  if (l == 0) {
    float s1 = 0.f, s2 = 0.f;
    #pragma unroll
    for (int c = 0; c < NCLS; ++c) {
      Wh2[n * NCLS + c] = acc[c];
      s1 += acc[c] * ao1[c];
      s2 += acc[c] * ao2[c];
    }
    g1[n] = s1; g2[n] = s2;
    Eg1[n]  = __expf(s1); Eg1s[n] = __expf(GAT_ALPHA * s1);
    Eg2[n]  = __expf(s2); Eg2s[n] = __expf(GAT_ALPHA * s2);
  }
}

// ---------------- ATT2 + log_softmax (no-max, separable exp) ---------------
__global__ __launch_bounds__(256) void att2_kernel(
    const unsigned long long* __restrict__ adjbits,
    const float* __restrict__ g1, const float* __restrict__ g2,
    const float* __restrict__ Eg1, const float* __restrict__ Eg1s,
    const float* __restrict__ Eg2, const float* __restrict__ Eg2s,
    const float* __restrict__ Wh2, float* __restrict__ out) {
  int n = blockIdx.x * 4 + (threadIdx.x >> 6);
  int l = threadIdx.x & 63;
  const float t1  = -g1[n];
  const float e1  = Eg1[n];
  const float e1s = Eg1s[n];
  const unsigned long long* __restrict__ abrow = adjbits + (size_t)n * NWORD;
  float S = 0.f;
  float acc[NCLS] = {};
  for (int tb = 0; tb < N_NODES; tb += 64) {
    int m = tb + l;
    unsigned long long bits = abrow[tb >> 6];
    float f2v = g2[m];
    float p = (f2v > t1) ? (e1 * Eg2[m]) : (e1s * Eg2s[m]);
    p = ((bits >> l) & 1ull) ? p : 0.f;
    S += p;
    const float* wrow = Wh2 + m * NCLS;
    #pragma unroll
    for (int c = 0; c < NCLS; ++c) acc[c] += p * wrow[c];
  }
  #pragma unroll
  for (int off = 32; off > 0; off >>= 1) S += __shfl_xor(S, off, 64);
  #pragma unroll
  for (int c = 0; c < NCLS; ++c)
    #pragma unroll
    for (int off = 32; off > 0; off >>= 1) acc[c] += __shfl_xor(acc[c], off, 64);
  float rS = 1.0f / S;
  float lo[NCLS]; float mx = -1e30f;
  #pragma unroll
  for (int c = 0; c < NCLS; ++c) { lo[c] = acc[c] * rS; mx = fmaxf(mx, lo[c]); }
  float se = 0.f;
  #pragma unroll
  for (int c = 0; c < NCLS; ++c) se += __expf(lo[c] - mx);
  float lse = mx + __logf(se);
  if (l == 0) {
    #pragma unroll
    for (int c = 0; c < NCLS; ++c) out[n * NCLS + c] = lo[c] - lse;
  }
}

extern "C" void kernel_launch(void* const* d_in, const int* in_sizes, int n_in,
                              void* d_out, int out_size, void* d_ws, size_t ws_size,
                              hipStream_t stream) {
  (void)in_sizes; (void)n_in; (void)out_size; (void)ws_size;
  const float* x   = (const float*)d_in[0];
  const int*   adj = (const int*)d_in[1];
  const float* W   = (const float*)d_in[2];
  const float* a1  = (const float*)d_in[3];
  const float* a2  = (const float*)d_in[4];
  const float* Wo  = (const float*)d_in[5];
  const float* ao1 = (const float*)d_in[6];
  const float* ao2 = (const float*)d_in[7];
  float* out = (float*)d_out;

  char* ws = (char*)d_ws;
  unsigned long long* adjbits = (unsigned long long*)ws; ws += (size_t)N_NODES * NWORD * 8;
  float* Whcat        = (float*)ws;          ws += (size_t)N_NODES * HID * 4;
  unsigned short* WhbT= (unsigned short*)ws; ws += (size_t)HID * WST * 2;
  unsigned short* hcat= (unsigned short*)ws; ws += (size_t)N_NODES * HID * 2;
  float* accP         = (float*)ws;          ws += (size_t)MSPLIT * N_NODES * HID * 4;
  float* SP           = (float*)ws;          ws += (size_t)MSPLIT * NHEAD * N_NODES * 4;
  float* f1           = (float*)ws;          ws += (size_t)NHEAD * N_NODES * 4;
  float* f2           = (float*)ws;          ws += (size_t)NHEAD * N_NODES * 4;
  float* E1           = (float*)ws;          ws += (size_t)NHEAD * N_NODES * 4;
  float* E1s          = (float*)ws;          ws += (size_t)NHEAD * N_NODES * 4;
  float* E2           = (float*)ws;          ws += (size_t)NHEAD * N_NODES * 4;
  float* E2s          = (float*)ws;          ws += (size_t)NHEAD * N_NODES * 4;
  float* Wh2          = (float*)ws;          ws += (size_t)N_NODES * NCLS * 4;
  float* g1           = (float*)ws;          ws += (size_t)N_NODES * 4;
  float* g2           = (float*)ws;          ws += (size_t)N_NODES * 4;
  float* Eg1          = (float*)ws;          ws += (size_t)N_NODES * 4;
  float* Eg1s         = (float*)ws;          ws += (size_t)N_NODES * 4;
  float* Eg2          = (float*)ws;          ws += (size_t)N_NODES * 4;
  float* Eg2s         = (float*)ws;          ws += (size_t)N_NODES * 4;

  pack_adj_kernel<<<N_NODES * NWORD / 4, 256, 0, stream>>>(adj, adjbits);
  gemm1_kernel<<<dim3(64, 8), 256, 0, stream>>>(x, W, Whcat, WhbT);
  f12_kernel<<<N_NODES, 512, 0, stream>>>(Whcat, a1, a2, f1, f2, E1, E1s, E2, E2s);
  att1_kernel<<<dim3(N_NODES / 64, MSPLIT), 512, 0, stream>>>(adjbits, f1, f2, E1, E1s, E2, E2s, WhbT, accP, SP);
  att1_reduce_kernel<<<N_NODES, 512, 0, stream>>>(accP, SP, hcat);
  gemm2_kernel<<<N_NODES / 4, 256, 0, stream>>>(hcat, Wo, ao1, ao2, Wh2, g1, g2, Eg1, Eg1s, Eg2, Eg2s);
  att2_kernel<<<N_NODES / 4, 256, 0, stream>>>(adjbits, g1, g2, Eg1, Eg1s, Eg2, Eg2s, Wh2, out);
}